// Round 4
// baseline (493.617 us; speedup 1.0000x reference)
//
#include <hip/hip_runtime.h>
#include <hip/hip_bf16.h>

// GraphConvolutionLayer on MI355X (gfx950)
//   scale = 1/(rowsum(adj)+beta);  agg = adj@x + beta*x;  out = (scale*agg)@W + bias
// R4: barrier-free K-loops. stage1/stage2 load MFMA fragments DIRECTLY from
//     global to registers (no LDS, no __syncthreads in the hot loop), letting
//     the compiler pipeline with fine-grained vmcnt — the memory-bound analog
//     of the AITER interleaved K-loop. A (adj, fp32) frag gather is 64B/128B
//     line-efficient; B comes from the pre-tiled bf16 xbt/wbt (contiguous
//     1 KB per instruction, L2-resident). Intra-block 2x redundancy is
//     L1-absorbed (per-step working set 24 KB < 32 KB L1).

typedef __attribute__((ext_vector_type(8))) short  short8;
typedef __attribute__((ext_vector_type(4))) float  floatx4;

#define N_NODES 8192
#define F_DIM   256

// fp32 -> bf16 round-to-nearest-even (finite inputs)
__device__ __forceinline__ unsigned short f2bf(float f) {
  unsigned u = __float_as_uint(f);
  return (unsigned short)((u + 0x7FFFu + ((u >> 16) & 1u)) >> 16);
}

__device__ __forceinline__ short8 pack_bf16x8(floatx4 a, floatx4 b) {
  short8 r;
  r[0] = (short)f2bf(a.x); r[1] = (short)f2bf(a.y);
  r[2] = (short)f2bf(a.z); r[3] = (short)f2bf(a.w);
  r[4] = (short)f2bf(b.x); r[5] = (short)f2bf(b.y);
  r[6] = (short)f2bf(b.z); r[7] = (short)f2bf(b.w);
  return r;
}

// ---------------------------------------------------------------------------
// k1: fp32 [K][256] -> bf16 tiled [K/32][n16(16)][kg(4)][nl(16)][8]
// Lane (kg,nl) of a B-fragment for (kblk,n16) then reads 16 contiguous bytes.
// ---------------------------------------------------------------------------
__global__ __launch_bounds__(256) void tile_bf16_kernel(
    const float* __restrict__ src, unsigned short* __restrict__ dst, int K) {
  const int Nn = F_DIM;
  int cid = blockIdx.x * 256 + threadIdx.x;
  int per_kblk = Nn * 4;
  int kblk = cid / per_kblk;
  int rem  = cid - kblk * per_kblk;
  int n16 = rem >> 6;
  int kg  = (rem >> 4) & 3;
  int nl  = rem & 15;
  int n = n16 * 16 + nl;
  int k = kblk * 32 + kg * 8;
  const float* s = src + (size_t)k * Nn + n;
  floatx4 v0, v1;
  v0.x = s[0];
  v0.y = s[(size_t)Nn];
  v0.z = s[(size_t)2 * Nn];
  v0.w = s[(size_t)3 * Nn];
  v1.x = s[(size_t)4 * Nn];
  v1.y = s[(size_t)5 * Nn];
  v1.z = s[(size_t)6 * Nn];
  v1.w = s[(size_t)7 * Nn];
  *(short8*)(dst + (size_t)cid * 8) = pack_bf16x8(v0, v1);
}

// ---------------------------------------------------------------------------
// k2: stage1 — partial agg (adj @ x) + partial rowsums. NO LDS, NO barriers.
// grid: dim3(128, KS), block 256 (4 waves).
// Block tile 64(M) x 256(N); wave (h=row-half, c=col-half): 32 x 128,
// mf=2, nf=8, acc = 16 floatx4. Per step (K=32): 4 A dwordx4 + 8 B dwordx4,
// 16 MFMA. Compiler pipelines across steps (no sync points).
// ---------------------------------------------------------------------------
template <int KS>
__global__ __launch_bounds__(256, 3) void stage1_kernel(
    const float* __restrict__ adj, const unsigned short* __restrict__ xbt,
    float* __restrict__ part, float* __restrict__ rsp) {
  const int tid = threadIdx.x;
  const int w   = tid >> 6;
  const int h   = w >> 1;        // row-half
  const int c   = w & 1;         // col-half
  const int l   = tid & 63;
  const int kq  = l >> 4;
  const int ml  = l & 15;
  const int m0  = blockIdx.x * 64;
  const int ks  = blockIdx.y;
  const int kbeg  = ks * (N_NODES / KS);
  const int STEPS = (N_NODES / KS) / 32;

  // A: lane (kq,ml), step s, mf: adj[m0+h*32+mf*16+ml][kbeg+s*32+kq*8 .. +7]
  const float* abase = adj + (size_t)(m0 + h * 32 + ml) * N_NODES + kbeg + kq * 8;
  // B: tiled xbt; fragment (kblk=kbeg/32+s, n16=c*8+nf) -> lane reads l*16 B
  const unsigned short* bbase =
      xbt + (size_t)(kbeg / 32) * (32 * F_DIM) + (c * 8) * 512 + kq * 128 + ml * 8;

  floatx4 acc[2][8];
  const floatx4 zf4 = {0.f, 0.f, 0.f, 0.f};
#pragma unroll
  for (int mf = 0; mf < 2; ++mf)
#pragma unroll
    for (int nf = 0; nf < 8; ++nf) acc[mf][nf] = zf4;
  float rsum[2] = {0.f, 0.f};

  for (int s = 0; s < STEPS; ++s) {
    floatx4 a0[2], a1[2];
#pragma unroll
    for (int mf = 0; mf < 2; ++mf) {
      const float* p = abase + (size_t)mf * 16 * N_NODES + s * 32;
      a0[mf] = *(const floatx4*)p;
      a1[mf] = *(const floatx4*)(p + 4);
    }
    short8 bv[8];
#pragma unroll
    for (int nf = 0; nf < 8; ++nf)
      bv[nf] = *(const short8*)(bbase + (size_t)s * (32 * F_DIM) + nf * 512);

    short8 af[2];
#pragma unroll
    for (int mf = 0; mf < 2; ++mf) {
      if (c == 0)   // fused rowsum (col-half 0 owns it; wave-uniform branch)
        rsum[mf] += (a0[mf].x + a0[mf].y + a0[mf].z + a0[mf].w) +
                    (a1[mf].x + a1[mf].y + a1[mf].z + a1[mf].w);
      af[mf] = pack_bf16x8(a0[mf], a1[mf]);
    }
#pragma unroll
    for (int nf = 0; nf < 8; ++nf)
#pragma unroll
      for (int mf = 0; mf < 2; ++mf)
        acc[mf][nf] = __builtin_amdgcn_mfma_f32_16x16x32_bf16(
            af[mf], bv[nf], acc[mf][nf], 0, 0, 0);
  }

  // C/D layout: col=lane&15, row=quad*4+reg (m89-verified)
  float* pout = part + (size_t)ks * N_NODES * F_DIM;
#pragma unroll
  for (int mf = 0; mf < 2; ++mf)
#pragma unroll
    for (int nf = 0; nf < 8; ++nf) {
      int col = c * 128 + nf * 16 + ml;
#pragma unroll
      for (int r = 0; r < 4; ++r) {
        int row = m0 + h * 32 + mf * 16 + kq * 4 + r;
        pout[(size_t)row * F_DIM + col] = acc[mf][nf][r];
      }
    }

  if (c == 0) {
#pragma unroll
    for (int mf = 0; mf < 2; ++mf) {
      float v = rsum[mf];
      v += __shfl_xor(v, 16);
      v += __shfl_xor(v, 32);
      if (kq == 0) rsp[ks * N_NODES + m0 + h * 32 + mf * 16 + ml] = v;
    }
  }
}

// ---------------------------------------------------------------------------
// k3: stage2 — out = (scale * (sum partials + beta*x)) @ W + bias.
// NO LDS; grid 512 blocks x 16 rows, block 256 (4 col-quarter waves).
// Each lane builds its own A-fragment from x + KS partials (register-side
// scale/convert), B direct from tiled wbt (L2-resident). One __syncthreads
// before the epilogue only for the KS==1 in-place (part==out) fallback.
// ---------------------------------------------------------------------------
template <int KS>
__global__ __launch_bounds__(256, 3) void stage2_kernel(
    const float* part, const float* __restrict__ rsp,
    const float* __restrict__ x, const float* __restrict__ beta,
    const float* __restrict__ bias, const unsigned short* __restrict__ wbt,
    float* out) {
  const int tid = threadIdx.x;
  const int w   = tid >> 6;       // col quarter
  const int l   = tid & 63;
  const int kq  = l >> 4;
  const int ml  = l & 15;
  const int m0  = blockIdx.x * 16;
  const int row = m0 + ml;

  float bb = beta[row];
  float rs = 0.f;
#pragma unroll
  for (int p = 0; p < KS; ++p) rs += rsp[p * N_NODES + row];
  const float sc = 1.0f / (rs + bb);

  floatx4 acc[4];
  const floatx4 zf4 = {0.f, 0.f, 0.f, 0.f};
#pragma unroll
  for (int nf = 0; nf < 4; ++nf) acc[nf] = zf4;

  const size_t rowoff = (size_t)row * F_DIM + kq * 8;

  for (int s = 0; s < 8; ++s) {
    size_t off = rowoff + s * 32;
    floatx4 v0 = *(const floatx4*)(x + off);
    floatx4 v1 = *(const floatx4*)(x + off + 4);
    v0 *= bb; v1 *= bb;
#pragma unroll
    for (int p = 0; p < KS; ++p) {
      const float* pp = part + (size_t)p * N_NODES * F_DIM + off;
      v0 += *(const floatx4*)pp;
      v1 += *(const floatx4*)(pp + 4);
    }
    v0 *= sc; v1 *= sc;
    short8 af = pack_bf16x8(v0, v1);
#pragma unroll
    for (int nf = 0; nf < 4; ++nf) {
      short8 bv = *(const short8*)(wbt + (size_t)s * (32 * F_DIM) +
                                   (w * 4 + nf) * 512 + kq * 128 + ml * 8);
      acc[nf] = __builtin_amdgcn_mfma_f32_16x16x32_bf16(af, bv, acc[nf], 0, 0, 0);
    }
  }

  __syncthreads();  // KS==1 fallback aliases part==out: all reads before writes

#pragma unroll
  for (int nf = 0; nf < 4; ++nf) {
    int col = w * 64 + nf * 16 + ml;
    float bvs = bias[col];
#pragma unroll
    for (int r = 0; r < 4; ++r)
      out[(size_t)(m0 + kq * 4 + r) * F_DIM + col] = acc[nf][r] + bvs;
  }
}

// ---------------------------------------------------------------------------
extern "C" void kernel_launch(void* const* d_in, const int* in_sizes, int n_in,
                              void* d_out, int out_size, void* d_ws, size_t ws_size,
                              hipStream_t stream) {
  const float* x    = (const float*)d_in[0];  // [8192][256]
  const float* adj  = (const float*)d_in[1];  // [8192][8192]
  const float* kern = (const float*)d_in[2];  // [256][256]
  const float* bias = (const float*)d_in[3];  // [256]
  const float* beta = (const float*)d_in[4];  // [8192]
  float* out = (float*)d_out;

  char* ws = (char*)d_ws;
  unsigned short* xbt = (unsigned short*)ws;                 // 4 MB
  unsigned short* wbt = xbt + (size_t)N_NODES * F_DIM;       // 128 KB
  float* rsp  = (float*)(wbt + F_DIM * F_DIM);               // 256 KB (KS<=8)
  float* part = (float*)((char*)rsp + 8 * N_NODES * sizeof(float));

  const size_t base    = (size_t)N_NODES * F_DIM * 2 + (size_t)F_DIM * F_DIM * 2 +
                         8 * (size_t)N_NODES * 4;
  const size_t part_sz = (size_t)N_NODES * F_DIM * 4;        // 8 MB per split

  tile_bf16_kernel<<<(N_NODES * F_DIM / 8) / 256, 256, 0, stream>>>(x, xbt, N_NODES);
  tile_bf16_kernel<<<(F_DIM * F_DIM / 8) / 256, 256, 0, stream>>>(kern, wbt, F_DIM);

  if (ws_size >= base + 8 * part_sz) {
    stage1_kernel<8><<<dim3(128, 8), 256, 0, stream>>>(adj, xbt, part, rsp);
    stage2_kernel<8><<<512, 256, 0, stream>>>(part, rsp, x, beta, bias, wbt, out);
  } else if (ws_size >= base + 4 * part_sz) {
    stage1_kernel<4><<<dim3(128, 4), 256, 0, stream>>>(adj, xbt, part, rsp);
    stage2_kernel<4><<<512, 256, 0, stream>>>(part, rsp, x, beta, bias, wbt, out);
  } else {
    // fallback: aggregate lives in d_out; stage2 rewrites it in place (row-local)
    stage1_kernel<1><<<dim3(128, 1), 256, 0, stream>>>(adj, xbt, out, rsp);
    stage2_kernel<1><<<512, 256, 0, stream>>>(out, rsp, x, beta, bias, wbt, out);
  }
}